// Round 1
// baseline (38.073 us; speedup 1.0000x reference)
//
#include <hip/hip_runtime.h>

#define NJ 24
#define BLK 128
#define OUTW 75              // (NJ+1)*3 floats per row
#define ROWF (BLK * OUTW)    // 9600 floats of LDS out-staging per block

__global__ __launch_bounds__(BLK) void fk_main_kernel(
    const float* __restrict__ ang,   // (B, 24)
    const float* __restrict__ xyz,   // (24, 3)
    const float* __restrict__ rpy,   // (24, 3)
    const float* __restrict__ axis,  // (24, 3)
    float* __restrict__ out)         // (B, 75)
{
    __shared__ float lcst[NJ * 16];      // per joint: Ro[9], xyz[3], u[3], n
    __shared__ float4 buf4[ROWF / 4];    // union: angle staging then output staging
    float* buf = (float*)buf4;

    const int tid = threadIdx.x;
    const long long b0 = (long long)blockIdx.x * BLK;

    // ---- per-joint constants (lanes 0..23) ----
    if (tid < NJ) {
        const int j = tid;
        float r = rpy[j*3+0], p = rpy[j*3+1], yv = rpy[j*3+2];
        float sr, cr, sp, cp, sy, cy;
        __sincosf(r, &sr, &cr);
        __sincosf(p, &sp, &cp);
        __sincosf(yv, &sy, &cy);
        float* c = &lcst[j * 16];
        c[0] = cy*cp; c[1] = cy*sp*sr - sy*cr; c[2] = cy*sp*cr + sy*sr;
        c[3] = sy*cp; c[4] = sy*sp*sr + cy*cr; c[5] = sy*sp*cr - cy*sr;
        c[6] = -sp;   c[7] = cp*sr;            c[8] = cp*cr;
        c[9]  = xyz[j*3+0]; c[10] = xyz[j*3+1]; c[11] = xyz[j*3+2];
        float ax = axis[j*3+0], ay = axis[j*3+1], az = axis[j*3+2];
        float n = sqrtf(ax*ax + ay*ay + az*az);
        float inv = 1.0f / fmaxf(n, 1e-6f);
        c[12] = ax*inv; c[13] = ay*inv; c[14] = az*inv; c[15] = n;
    }

    // ---- stage this block's angles, coalesced, into padded LDS rows ----
    const float* gA = ang + b0 * NJ;
    #pragma unroll
    for (int k = 0; k < NJ; ++k) {
        int i = tid + k * BLK;
        int r = i / NJ, c = i - r * NJ;
        buf[r * 25 + c] = gA[i];     // stride 25 (odd) -> conflict-free reads
    }
    __syncthreads();

    // my row's angles -> registers (static indexing only)
    float th[NJ];
    #pragma unroll
    for (int j = 0; j < NJ; ++j) th[j] = buf[tid * 25 + j];
    __syncthreads();   // buf is reused for output staging below

    // ---- FK scan ----
    float Rp0=1.f,Rp1=0.f,Rp2=0.f,Rp3=0.f,Rp4=1.f,Rp5=0.f,Rp6=0.f,Rp7=0.f,Rp8=1.f;
    float t0=0.f, t1=0.f, t2=0.f;
    float* ob = &buf[tid * OUTW];    // stride 75 (odd) -> conflict-free writes
    ob[0] = 0.f; ob[1] = 0.f; ob[2] = 0.f;

    #pragma unroll
    for (int j = 0; j < NJ; ++j) {
        const float* c = &lcst[j * 16];   // wave-uniform -> LDS broadcast
        float a = th[j] * c[15];
        float s, ca;
        __sincosf(a, &s, &ca);
        float oc = 1.0f - ca;
        float ux = c[12], uy = c[13], uz = c[14];
        float xs = ux*s, ys = uy*s, zs = uz*s;
        float xo = ux*oc, yo = uy*oc, zo = uz*oc;
        float R00 = ca + ux*xo, R01 = ux*yo - zs, R02 = ux*zo + ys;
        float R10 = uy*xo + zs, R11 = ca + uy*yo, R12 = uy*zo - xs;
        float R20 = uz*xo - ys, R21 = uz*yo + xs, R22 = ca + uz*zo;

        // t += Rp * xyz   (uses parent rotation, before update)
        float x = c[9], y = c[10], z = c[11];
        t0 += Rp0*x + Rp1*y + Rp2*z;
        t1 += Rp3*x + Rp4*y + Rp5*z;
        t2 += Rp6*x + Rp7*y + Rp8*z;

        // A = Rp * Ro
        float O0=c[0],O1=c[1],O2=c[2],O3=c[3],O4=c[4],O5=c[5],O6=c[6],O7=c[7],O8=c[8];
        float A0 = Rp0*O0 + Rp1*O3 + Rp2*O6;
        float A1 = Rp0*O1 + Rp1*O4 + Rp2*O7;
        float A2 = Rp0*O2 + Rp1*O5 + Rp2*O8;
        float A3 = Rp3*O0 + Rp4*O3 + Rp5*O6;
        float A4 = Rp3*O1 + Rp4*O4 + Rp5*O7;
        float A5 = Rp3*O2 + Rp4*O5 + Rp5*O8;
        float A6 = Rp6*O0 + Rp7*O3 + Rp8*O6;
        float A7 = Rp6*O1 + Rp7*O4 + Rp8*O7;
        float A8 = Rp6*O2 + Rp7*O5 + Rp8*O8;

        // Rp = A * R
        Rp0 = A0*R00 + A1*R10 + A2*R20;
        Rp1 = A0*R01 + A1*R11 + A2*R21;
        Rp2 = A0*R02 + A1*R12 + A2*R22;
        Rp3 = A3*R00 + A4*R10 + A5*R20;
        Rp4 = A3*R01 + A4*R11 + A5*R21;
        Rp5 = A3*R02 + A4*R12 + A5*R22;
        Rp6 = A6*R00 + A7*R10 + A8*R20;
        Rp7 = A6*R01 + A7*R11 + A8*R21;
        Rp8 = A6*R02 + A7*R12 + A8*R22;

        ob[3*(j+1)+0] = t0;
        ob[3*(j+1)+1] = t1;
        ob[3*(j+1)+2] = t2;
    }
    __syncthreads();

    // ---- coalesced float4 dump of the block's (128 x 75) output chunk ----
    float4* gO = (float4*)(out + b0 * OUTW);   // 9600 floats -> 2400 float4
    #pragma unroll
    for (int k = 0; k < (ROWF/4 + BLK - 1) / BLK; ++k) {
        int i = tid + k * BLK;
        if (i < ROWF / 4) gO[i] = buf4[i];
    }
}

extern "C" void kernel_launch(void* const* d_in, const int* in_sizes, int n_in,
                              void* d_out, int out_size, void* d_ws, size_t ws_size,
                              hipStream_t stream) {
    const float* ang  = (const float*)d_in[0];
    const float* xyz  = (const float*)d_in[1];
    const float* rpy  = (const float*)d_in[2];
    const float* axis = (const float*)d_in[3];
    float* out = (float*)d_out;

    const int B = in_sizes[0] / NJ;          // 262144
    const int grid = (B + BLK - 1) / BLK;    // 2048
    fk_main_kernel<<<grid, BLK, 0, stream>>>(ang, xyz, rpy, axis, out);
}